// Round 4
// baseline (308.901 us; speedup 1.0000x reference)
//
#include <hip/hip_runtime.h>
#include <stdint.h>

// IterNorm (BWItnBlock): out = wm*x + (beta - wm*mu),  wm = Sigma^{-1/2}
// R4 = R3 with the swizzle-bijection fix: 128-wide rows have 16 granules;
//     XOR only the low 3 granule bits and PRESERVE bit 3 (col&64). R3's swz
//     folded col and col+64 onto the same LDS word -> garbage wm (absmax 408).

#define CC    128
#define HWs   3136
#define MM    200704
#define EPSv  1e-5f
#define NS_ITERS 5

typedef __attribute__((ext_vector_type(8))) short  bfrag;
typedef __attribute__((ext_vector_type(4))) short  short4v;
typedef __attribute__((ext_vector_type(4))) float  f32x4;

__device__ __forceinline__ unsigned short f2bf(float x) {
  union { float f; unsigned u; } v; v.f = x;
  unsigned r = (v.u + 0x7FFFu + ((v.u >> 16) & 1u)) >> 16;
  return (unsigned short)r;
}
__device__ __forceinline__ float bf2f(unsigned short h) {
  union { float f; unsigned u; } v; v.u = ((unsigned)h) << 16;
  return v.f;
}
// XOR swizzle, 128-wide rows (16 granules of 8 bf16 = 16B):
// granule' = (granule&8) | ((granule ^ row) & 7)  -- bijective, keeps 16B
// fragment reads contiguous, spreads 8-consecutive-row phases over 8 granules
// (= all 32 banks).
__device__ __forceinline__ int swz(int row, int col) {
  return (row << 7) + (col & 64) + ((((col >> 3) ^ row) & 7) << 3) + (col & 7);
}
// 64-wide rows: exactly 8 granules, plain XOR is bijective.
__device__ __forceinline__ int swz64(int row, int col) {
  return (row << 6) + ((((col >> 3) ^ row) & 7) << 3) + (col & 7);
}

// ---------------- K1: partial Gram + channel sums ----------------
__device__ __forceinline__ void k1_load(float4* vals, const float* rowptr,
                                        int ck, int q) {
#pragma unroll
  for (int u = 0; u < 4; ++u) {
    const int sl = ck * 64 + q * 16 + 4 * u;
    if (sl + 4 <= 784) vals[u] = *(const float4*)(rowptr + sl);
    else               vals[u] = make_float4(0.f, 0.f, 0.f, 0.f);
  }
}

__global__ __launch_bounds__(512, 4) void k1_gram(const float* __restrict__ X,
                                                  float* __restrict__ partials,
                                                  float* __restrict__ colsum) {
  __shared__ unsigned short Xs[CC * 64];
  __shared__ float red[512];
  const int t = threadIdx.x;
  const int lane = t & 63;
  const int wave = t >> 6;          // 0..7
  const int m15 = lane & 15;
  const int quad = lane >> 4;
  const int bid = blockIdx.x;       // 256 blocks: (n, quarter)
  const int n = bid >> 2;
  const int qq = bid & 3;
  const int c = t & 127;            // channel row this thread loads
  const int q = t >> 7;             // 16-sample slice 0..3
  const float* rowptr = X + ((size_t)(n * CC + c)) * HWs + qq * 784;

  f32x4 acc[8];
#pragma unroll
  for (int j = 0; j < 8; ++j) acc[j] = (f32x4){0.f, 0.f, 0.f, 0.f};
  float fsum = 0.f;

  float4 vals[4];
  k1_load(vals, rowptr, 0, q);           // prologue

  for (int ck = 0; ck < 13; ++ck) {      // 13*64 = 832 >= 784, tail zero-padded
    __syncthreads();                     // prev chunk's MFMA reads complete
#pragma unroll
    for (int u = 0; u < 4; ++u) {
      fsum += vals[u].x + vals[u].y + vals[u].z + vals[u].w;
      short4v pk;
      pk.x = (short)f2bf(vals[u].x);
      pk.y = (short)f2bf(vals[u].y);
      pk.z = (short)f2bf(vals[u].z);
      pk.w = (short)f2bf(vals[u].w);
      *(short4v*)&Xs[swz64(c, q * 16 + 4 * u)] = pk;   // 4-elem aligned: one granule
    }
    if (ck < 12) k1_load(vals, rowptr, ck + 1, q);     // issue next loads here:
    __syncthreads();                                   // drain covered by MFMA below
#pragma unroll
    for (int kc = 0; kc < 2; ++kc) {
      const int k0 = kc * 32 + quad * 8;
      const bfrag a = *(const bfrag*)&Xs[swz64(wave * 16 + m15, k0)];
      bfrag b[8];
#pragma unroll
      for (int j = 0; j < 8; ++j)
        b[j] = *(const bfrag*)&Xs[swz64(j * 16 + m15, k0)];
#pragma unroll
      for (int j = 0; j < 8; ++j)
        acc[j] = __builtin_amdgcn_mfma_f32_16x16x32_bf16(a, b[j], acc[j], 0, 0, 0);
    }
  }

  float* slot = partials + (size_t)bid * 16384;
#pragma unroll
  for (int j = 0; j < 8; ++j)
#pragma unroll
    for (int r = 0; r < 4; ++r) {
      const int row = wave * 16 + quad * 4 + r;
      const int col = j * 16 + m15;
      slot[row * 128 + col] = acc[j][r];
    }

  __syncthreads();
  red[t] = fsum;
  __syncthreads();
  if (t < 128)
    atomicAdd(&colsum[t], red[t] + red[t + 128] + red[t + 256] + red[t + 384]);
}

// ---------------- K1b: reduce partials -> Sigma, mean, trace ----------------
__global__ __launch_bounds__(128) void k1b_reduce(const float* __restrict__ partials,
                                                  const float* __restrict__ colsum,
                                                  float* __restrict__ Sigma,
                                                  float* __restrict__ meanb,
                                                  float* __restrict__ traceb) {
  const int e = blockIdx.x * 128 + threadIdx.x;   // 128 blocks * 128 = 16384
  float s0 = 0.f, s1 = 0.f, s2 = 0.f, s3 = 0.f;
  for (int p = 0; p < 256; p += 4) {
    s0 += partials[(size_t)(p + 0) * 16384 + e];
    s1 += partials[(size_t)(p + 1) * 16384 + e];
    s2 += partials[(size_t)(p + 2) * 16384 + e];
    s3 += partials[(size_t)(p + 3) * 16384 + e];
  }
  const float s = (s0 + s1) + (s2 + s3);
  const int row = e >> 7, col = e & 127;
  const float inv_m = 1.0f / (float)MM;
  const float mr = colsum[row] * inv_m;
  const float mc = colsum[col] * inv_m;
  float sig = s * inv_m - mr * mc;
  if (row == col) sig += EPSv;
  Sigma[e] = sig;
  if (row == col) atomicAdd(traceb, sig);
  if (e < 128) meanb[e] = colsum[e] * inv_m;
}

// ---------------- K2 helpers (swizzled 128x128 buffers) ----------------
__device__ __forceinline__ void mmq(f32x4 acc[4][4], const unsigned short* A,
                                    const unsigned short* B, int r0, int c0,
                                    int m15, int quad) {
#pragma unroll
  for (int i = 0; i < 4; ++i)
#pragma unroll
    for (int j = 0; j < 4; ++j) acc[i][j] = (f32x4){0.f, 0.f, 0.f, 0.f};
#pragma unroll
  for (int kc = 0; kc < 4; ++kc) {
    const int k0 = kc * 32 + quad * 8;
    bfrag a[4], b[4];
#pragma unroll
    for (int i = 0; i < 4; ++i)
      a[i] = *(const bfrag*)&A[swz(r0 + i * 16 + m15, k0)];
#pragma unroll
    for (int j = 0; j < 4; ++j)
      b[j] = *(const bfrag*)&B[swz(c0 + j * 16 + m15, k0)];  // symmetric operand
#pragma unroll
    for (int i = 0; i < 4; ++i)
#pragma unroll
      for (int j = 0; j < 4; ++j)
        acc[i][j] = __builtin_amdgcn_mfma_f32_16x16x32_bf16(a[i], b[j], acc[i][j], 0, 0, 0);
  }
}

__device__ __forceinline__ void storeq(unsigned short* D, f32x4 acc[4][4],
                                       int r0, int c0, int m15, int quad) {
#pragma unroll
  for (int i = 0; i < 4; ++i)
#pragma unroll
    for (int j = 0; j < 4; ++j)
#pragma unroll
      for (int r = 0; r < 4; ++r)
        D[swz(r0 + i * 16 + quad * 4 + r, c0 + j * 16 + m15)] = f2bf(acc[i][j][r]);
}

// ---------------- K2: Newton-Schulz, single block, 3 barriers/iter ----------
__global__ __launch_bounds__(256) void k2_ns(const float* __restrict__ Sigma,
                                             const float* __restrict__ tracep,
                                             float* __restrict__ wm) {
  extern __shared__ unsigned short lds2[];
  unsigned short* P = lds2;                 // 128x128 each, swizzled
  unsigned short* S = lds2 + 16384;
  unsigned short* T = lds2 + 32768;
  unsigned short* U = lds2 + 49152;
  const int t = threadIdx.x;
  const int lane = t & 63, wave = t >> 6;
  const int m15 = lane & 15, quad = lane >> 4;
  const float tr = tracep[0];
  const float sc = 128.0f / tr;             // mean-eigenvalue normalization
  for (int e = t; e < 16384; e += 256) {
    const int r = e >> 7, cl = e & 127;
    S[swz(r, cl)] = f2bf(Sigma[e] * sc);
    P[swz(r, cl)] = (r == cl) ? (unsigned short)0x3F80 : (unsigned short)0;
  }
  __syncthreads();
  const int r0 = (wave >> 1) * 64, c0 = (wave & 1) * 64;
  f32x4 acc[4][4];
  for (int it = 0; it < NS_ITERS; ++it) {
    mmq(acc, P, P, r0, c0, m15, quad);      // T = P @ P
    storeq(T, acc, r0, c0, m15, quad);
    __syncthreads();
    mmq(acc, T, P, r0, c0, m15, quad);      // U = T @ P
    storeq(U, acc, r0, c0, m15, quad);
    __syncthreads();
    mmq(acc, U, S, r0, c0, m15, quad);      // acc = P^3 @ S
    if (it < NS_ITERS - 1) {
      // P update touches only this wave's own quadrant -> no extra barrier
#pragma unroll
      for (int i = 0; i < 4; ++i)
#pragma unroll
        for (int j = 0; j < 4; ++j)
#pragma unroll
          for (int r = 0; r < 4; ++r) {
            const int row = r0 + i * 16 + quad * 4 + r;
            const int col = c0 + j * 16 + m15;
            P[swz(row, col)] =
                f2bf(1.5f * bf2f(P[swz(row, col)]) - 0.5f * acc[i][j][r]);
          }
      __syncthreads();
    } else {
      const float ks = sqrtf(sc);           // wm = P_final * sqrt(128/tr)
#pragma unroll
      for (int i = 0; i < 4; ++i)
#pragma unroll
        for (int j = 0; j < 4; ++j)
#pragma unroll
          for (int r = 0; r < 4; ++r) {
            const int row = r0 + i * 16 + quad * 4 + r;
            const int col = c0 + j * 16 + m15;
            wm[row * 128 + col] =
                (1.5f * bf2f(P[swz(row, col)]) - 0.5f * acc[i][j][r]) * ks;
          }
    }
  }
}

// ---------------- K3: whitening GEMM + folded epilogue ----------------
__global__ __launch_bounds__(512, 4) void k3_whiten(const float* __restrict__ X,
                                                    const float* __restrict__ wmp,
                                                    const float* __restrict__ meanp,
                                                    const float* __restrict__ beta,
                                                    float* __restrict__ out) {
  extern __shared__ unsigned short lds3[];
  unsigned short* TH = lds3;                    // 128x128 swizzled, triple-reused
  float* offs = (float*)(lds3 + 16384);         // 128 floats: beta - wm*mu
  const int t = threadIdx.x;
  const int lane = t & 63, wave = t >> 6;       // 8 waves = 8 output rowtiles
  const int m15 = lane & 15, quad = lane >> 4;
  const int c = t & 127, q = t >> 7;            // loader: channel, 32-sample slice

  // phase A: stage wm-hi, grab hi A-frags, compute offs
  for (int e = t; e < 16384; e += 512) {
    const int r = e >> 7, cl = e & 127;
    TH[swz(r, cl)] = f2bf(wmp[e]);
  }
  __syncthreads();
  bfrag wah[4], wal[4];
#pragma unroll
  for (int kc = 0; kc < 4; ++kc)
    wah[kc] = *(const bfrag*)&TH[swz(wave * 16 + m15, kc * 32 + quad * 8)];
  if (t < 128) {
    float o = 0.f;
    for (int d = 0; d < 128; ++d) o += bf2f(TH[swz(t, d)]) * meanp[d];
    offs[t] = beta[t] - o;
  }
  __syncthreads();
  // phase B: stage wm-lo in the SAME buffer, grab lo A-frags
  for (int e = t; e < 16384; e += 512) {
    const int r = e >> 7, cl = e & 127;
    const float v = wmp[e];
    TH[swz(r, cl)] = f2bf(v - bf2f(f2bf(v)));
  }
  __syncthreads();
#pragma unroll
  for (int kc = 0; kc < 4; ++kc)
    wal[kc] = *(const bfrag*)&TH[swz(wave * 16 + m15, kc * 32 + quad * 8)];
  float bet[4];
#pragma unroll
  for (int r = 0; r < 4; ++r) bet[r] = offs[wave * 16 + quad * 4 + r];

  // phase C: grid-stride tiles of 128 flat samples; software-pipelined.
  float4 vals[8];
  {
    const int swin = blockIdx.x * 128 + 32 * q;
    const int n = swin / HWs, s = swin % HWs;
    const float* rp = X + ((size_t)(n * CC + c)) * HWs + s;
#pragma unroll
    for (int u = 0; u < 8; ++u) vals[u] = *(const float4*)(rp + 4 * u);
  }
  for (int g = blockIdx.x; g < 1568; g += 512) {
    __syncthreads();   // prev tile's fragment reads (or wal reads) complete
#pragma unroll
    for (int u = 0; u < 8; ++u) {
      const float4 v = vals[u];
      const int srow = 32 * q + 4 * u;
      TH[swz(srow + 0, c)] = f2bf(v.x);
      TH[swz(srow + 1, c)] = f2bf(v.y);
      TH[swz(srow + 2, c)] = f2bf(v.z);
      TH[swz(srow + 3, c)] = f2bf(v.w);
    }
    if (g + 512 < 1568) {                     // issue next tile's loads HERE:
      const int swin = (g + 512) * 128 + 32 * q;   // drain covered by MFMA below
      const int n = swin / HWs, s = swin % HWs;
      const float* rp = X + ((size_t)(n * CC + c)) * HWs + s;
#pragma unroll
      for (int u = 0; u < 8; ++u) vals[u] = *(const float4*)(rp + 4 * u);
    }
    __syncthreads();
#pragma unroll
    for (int ct = 0; ct < 8; ++ct) {
      f32x4 acc = (f32x4){0.f, 0.f, 0.f, 0.f};
#pragma unroll
      for (int kc = 0; kc < 4; ++kc) {
        const bfrag bh = *(const bfrag*)&TH[swz(ct * 16 + m15, kc * 32 + quad * 8)];
        acc = __builtin_amdgcn_mfma_f32_16x16x32_bf16(wah[kc], bh, acc, 0, 0, 0);
        acc = __builtin_amdgcn_mfma_f32_16x16x32_bf16(wal[kc], bh, acc, 0, 0, 0);
      }
      const int scol = g * 128 + ct * 16;     // 16-sample group within one n
      const int n2 = scol / HWs, s2 = scol % HWs;
      const int colx = s2 + m15;
#pragma unroll
      for (int r = 0; r < 4; ++r) {
        const int row = wave * 16 + quad * 4 + r;
        out[((size_t)(n2 * CC + row)) * HWs + colx] = acc[r] + bet[r];
      }
    }
  }
}

extern "C" void kernel_launch(void* const* d_in, const int* in_sizes, int n_in,
                              void* d_out, int out_size, void* d_ws, size_t ws_size,
                              hipStream_t stream) {
  const float* X    = (const float*)d_in[0];
  const float* beta = (const float*)d_in[1];
  float* out = (float*)d_out;
  float* ws  = (float*)d_ws;

  float* partials = ws;                                 // 256 * 16384
  float* Sigma    = ws + (size_t)256 * 16384;           // 16384
  float* wmb      = Sigma + 16384;                      // 16384
  float* colsum   = wmb + 16384;                        // 128
  float* meanb    = colsum + 128;                       // 128
  float* traceb   = meanb + 128;                        // 1

  hipMemsetAsync(colsum, 0, (128 + 128 + 1) * sizeof(float), stream);

  k1_gram<<<256, 512, 0, stream>>>(X, partials, colsum);
  k1b_reduce<<<128, 128, 0, stream>>>(partials, colsum, Sigma, meanb, traceb);

  const int lds_k2 = 4 * 16384 * (int)sizeof(unsigned short);            // 131072 B
  const int lds_k3 = 16384 * (int)sizeof(unsigned short) + 128 * (int)sizeof(float);
  (void)hipFuncSetAttribute((const void*)k2_ns,
                            hipFuncAttributeMaxDynamicSharedMemorySize, lds_k2);
  (void)hipFuncSetAttribute((const void*)k3_whiten,
                            hipFuncAttributeMaxDynamicSharedMemorySize, lds_k3);

  k2_ns<<<1, 256, lds_k2, stream>>>(Sigma, traceb, wmb);
  k3_whiten<<<512, 512, lds_k3, stream>>>(X, wmb, meanb, beta, out);
}